// Round 1
// baseline (331.152 us; speedup 1.0000x reference)
//
#include <hip/hip_runtime.h>
#include <hip/hip_bf16.h>
#include <stdint.h>

#define NEG_INF -100000000.0f

typedef __attribute__((ext_vector_type(8))) short bf16x8;
typedef __attribute__((ext_vector_type(4))) float f32x4;

static __device__ __forceinline__ short f2bf(float x) {
    unsigned u = __float_as_uint(x);
    u = u + 0x7FFFu + ((u >> 16) & 1u);
    return (short)(u >> 16);
}

// ---------------- kernel 1: transpose + bf16-convert weights ----------------
// w [256 k][256 c] f32  ->  wt [256 c][256 k] bf16
__global__ void wtrans_kernel(const float* __restrict__ wq, const float* __restrict__ wk,
                              short* __restrict__ wtq, short* __restrict__ wtk) {
    __shared__ float tile[32][33];
    const float* w = blockIdx.z ? wk : wq;
    short* wt = blockIdx.z ? wtk : wtq;
    int tx = threadIdx.x, ty = threadIdx.y;
    int c0 = blockIdx.x * 32;   // col block of w
    int k0 = blockIdx.y * 32;   // row block of w
#pragma unroll
    for (int i = 0; i < 4; i++)
        tile[ty + i * 8][tx] = w[(k0 + ty + i * 8) * 256 + c0 + tx];
    __syncthreads();
#pragma unroll
    for (int i = 0; i < 4; i++)
        wt[(c0 + ty + i * 8) * 256 + k0 + tx] = f2bf(tile[tx][ty + i * 8]);
}

// ---------------- kernel 2: projection GEMM  X[65536,256] @ W[256,256] -> bf16 ----------------
// blockIdx.y: 0 -> Q = q @ wq ; 1 -> K = k @ wk
__global__ __launch_bounds__(512, 4)
void proj_kernel(const float* __restrict__ qin, const float* __restrict__ kin,
                 const short* __restrict__ wtq, const short* __restrict__ wtk,
                 short* __restrict__ Qb, short* __restrict__ Kb) {
    const float* x  = blockIdx.y ? kin : qin;
    const short* wt = blockIdx.y ? wtk : wtq;   // [c 256][k 256] bf16
    short* outp     = blockIdx.y ? Kb  : Qb;

    __shared__ __align__(16) short xlds[64 * 32];    // [row][32 k], 64B row stride
    __shared__ __align__(16) short wlds[256 * 32];   // [c][32 k],  64B row stride

    int t = threadIdx.x;
    int lane = t & 63, w = t >> 6;
    int l15 = lane & 15, g = lane >> 4;
    int rowbase = blockIdx.x * 64;

    f32x4 zero = {0.f, 0.f, 0.f, 0.f};
    f32x4 acc[4][2];
#pragma unroll
    for (int m = 0; m < 4; m++)
#pragma unroll
        for (int n = 0; n < 2; n++) acc[m][n] = zero;

    for (int dc = 0; dc < 8; dc++) {
        __syncthreads();
        // stage X chunk [64 rows][32 k] f32 -> bf16
        {
            int row = t >> 3, seg = t & 7;
            float4 v = *reinterpret_cast<const float4*>(x + (size_t)(rowbase + row) * 256 + dc * 32 + seg * 4);
            short4 b;
            b.x = f2bf(v.x); b.y = f2bf(v.y); b.z = f2bf(v.z); b.w = f2bf(v.w);
            *reinterpret_cast<short4*>(&xlds[row * 32 + seg * 4]) = b;
        }
        // stage W^T chunk [256 c][32 k] bf16 (already bf16 in ws)
#pragma unroll
        for (int i = 0; i < 2; i++) {
            int idx = i * 512 + t;
            int c = idx >> 2, seg = idx & 3;
            int4 v = *reinterpret_cast<const int4*>(wt + c * 256 + dc * 32 + seg * 8);
            *reinterpret_cast<int4*>(&wlds[idx * 8]) = v;   // c*32 + seg*8 == idx*8
        }
        __syncthreads();

        bf16x8 a[4], bfr[2];
#pragma unroll
        for (int m = 0; m < 4; m++)
            a[m] = *reinterpret_cast<const bf16x8*>(&xlds[(m * 16 + l15) * 32 + g * 8]);
#pragma unroll
        for (int n = 0; n < 2; n++) {
            int c = w * 32 + n * 16 + l15;
            bfr[n] = *reinterpret_cast<const bf16x8*>(&wlds[c * 32 + g * 8]);
        }
#pragma unroll
        for (int m = 0; m < 4; m++)
#pragma unroll
            for (int n = 0; n < 2; n++)
                acc[m][n] = __builtin_amdgcn_mfma_f32_16x16x32_bf16(a[m], bfr[n], acc[m][n], 0, 0, 0);
    }

    // write out bf16: C layout col=lane&15, row=(lane>>4)*4+reg
#pragma unroll
    for (int m = 0; m < 4; m++)
#pragma unroll
        for (int n = 0; n < 2; n++)
#pragma unroll
            for (int r = 0; r < 4; r++) {
                int row = rowbase + m * 16 + g * 4 + r;
                int col = w * 32 + n * 16 + l15;
                outp[(size_t)row * 256 + col] = f2bf(acc[m][n][r]);
            }
}

// ---------------- kernel 3: fused QK^T + tanh-clip + mask + log_softmax ----------------
// block: 32 q-rows x 1024 k-cols, 8 waves (wave w owns cols w*128..+128)
__global__ __launch_bounds__(512, 4)
void attn_kernel(const short* __restrict__ Qg, const short* __restrict__ Kg,
                 const int* __restrict__ mask, float* __restrict__ out) {
    __shared__ __align__(16) char lds[81920];          // 80KB exactly -> 2 blocks/CU
    short* klds = (short*)lds;                         // [1024 c][32 k] per d-chunk (64KB)
    short* qlds = (short*)(lds + 65536);               // chunk-major [8][32 row][32 k] (16KB)
    float* redbuf = (float*)lds;                       // reused after MFMA: [8 w][32 row]
    float* lsebuf = (float*)(lds + 4096);              // [32]

    int t = threadIdx.x;
    int lane = t & 63, w = t >> 6;
    int l15 = lane & 15, g = lane >> 4;
    int b = blockIdx.y;
    int brow = blockIdx.x * 32;

    // stage Q tile (32 rows x 256 d) chunk-major, once
#pragma unroll
    for (int i = 0; i < 2; i++) {
        int idx = i * 512 + t;               // 1024 x 16B units
        int chunk = idx >> 7, rem = idx & 127;
        int row = rem >> 2, seg = rem & 3;
        int4 v = *reinterpret_cast<const int4*>(
            Qg + ((size_t)(b * 1024 + brow + row)) * 256 + chunk * 32 + seg * 8);
        *reinterpret_cast<int4*>(qlds + idx * 8) = v;
    }

    f32x4 zero = {0.f, 0.f, 0.f, 0.f};
    f32x4 acc[2][8];
#pragma unroll
    for (int m = 0; m < 2; m++)
#pragma unroll
        for (int n = 0; n < 8; n++) acc[m][n] = zero;

    const short* kbase = Kg + (size_t)b * 1024 * 256;

    for (int dc = 0; dc < 8; dc++) {
        __syncthreads();
        // stage K chunk [1024 c][32 k] (64KB), 8x16B per thread in 2 rounds
#pragma unroll
        for (int half = 0; half < 2; half++) {
            int4 tmp[4];
#pragma unroll
            for (int i = 0; i < 4; i++) {
                int idx = (half * 4 + i) * 512 + t;
                int row = idx >> 2, seg = idx & 3;
                tmp[i] = *reinterpret_cast<const int4*>(kbase + (size_t)row * 256 + dc * 32 + seg * 8);
            }
#pragma unroll
            for (int i = 0; i < 4; i++) {
                int idx = (half * 4 + i) * 512 + t;
                *reinterpret_cast<int4*>(klds + idx * 8) = tmp[i];
            }
        }
        __syncthreads();

        bf16x8 a[2];
#pragma unroll
        for (int m = 0; m < 2; m++)
            a[m] = *reinterpret_cast<const bf16x8*>(qlds + dc * 1024 + (m * 16 + l15) * 32 + g * 8);
#pragma unroll
        for (int n = 0; n < 8; n++) {
            int c = w * 128 + n * 16 + l15;
            bf16x8 bfrag = *reinterpret_cast<const bf16x8*>(klds + c * 32 + g * 8);
            acc[0][n] = __builtin_amdgcn_mfma_f32_16x16x32_bf16(a[0], bfrag, acc[0][n], 0, 0, 0);
            acc[1][n] = __builtin_amdgcn_mfma_f32_16x16x32_bf16(a[1], bfrag, acc[1][n], 0, 0, 0);
        }
    }
    __syncthreads();   // all MFMA LDS reads done; klds area reused below

    // epilogue: u = 10*tanh(acc/16); mask -> NEG_INF; rowsum of exp
    const float norml = 0.0625f;
    float rowsum[2][4];
#pragma unroll
    for (int m = 0; m < 2; m++)
#pragma unroll
        for (int r = 0; r < 4; r++) rowsum[m][r] = 0.f;

#pragma unroll
    for (int m = 0; m < 2; m++)
#pragma unroll
        for (int n = 0; n < 8; n++) {
            const int* mrow = mask + ((size_t)b * 1024 + brow + m * 16 + g * 4) * 1024
                              + w * 128 + n * 16 + l15;
#pragma unroll
            for (int r = 0; r < 4; r++) {
                float un = acc[m][n][r] * norml;
                float e2 = __expf(2.0f * un);
                float uc = 10.0f - 20.0f / (e2 + 1.0f);   // 10*tanh(un)
                int mv = mrow[(size_t)r * 1024];
                bool msk = (mv == 1);
                acc[m][n][r] = msk ? NEG_INF : uc;
                rowsum[m][r] += msk ? 0.0f : __expf(uc);
            }
        }

    // reduce across the 16 lanes sharing a row
#pragma unroll
    for (int m = 0; m < 2; m++)
#pragma unroll
        for (int r = 0; r < 4; r++) {
            float s = rowsum[m][r];
            s += __shfl_xor(s, 1);
            s += __shfl_xor(s, 2);
            s += __shfl_xor(s, 4);
            s += __shfl_xor(s, 8);
            rowsum[m][r] = s;
        }
    if (l15 == 0) {
#pragma unroll
        for (int m = 0; m < 2; m++)
#pragma unroll
            for (int r = 0; r < 4; r++)
                redbuf[w * 32 + m * 16 + g * 4 + r] = rowsum[m][r];
    }
    __syncthreads();
    if (t < 32) {
        float s = 0.f;
#pragma unroll
        for (int ww = 0; ww < 8; ww++) s += redbuf[ww * 32 + t];
        lsebuf[t] = __logf(fmaxf(s, 1e-30f));
    }
    __syncthreads();

    // write output: out = u - lse
    float* obase = out + ((size_t)b * 1024 + brow) * 1024;
#pragma unroll
    for (int m = 0; m < 2; m++)
#pragma unroll
        for (int r = 0; r < 4; r++) {
            int row_l = m * 16 + g * 4 + r;
            float lse = lsebuf[row_l];
#pragma unroll
            for (int n = 0; n < 8; n++) {
                int col = w * 128 + n * 16 + l15;
                obase[(size_t)row_l * 1024 + col] = acc[m][n][r] - lse;
            }
        }
}

extern "C" void kernel_launch(void* const* d_in, const int* in_sizes, int n_in,
                              void* d_out, int out_size, void* d_ws, size_t ws_size,
                              hipStream_t stream) {
    const float* q  = (const float*)d_in[0];
    const float* k  = (const float*)d_in[1];
    const float* wq = (const float*)d_in[2];
    const float* wk = (const float*)d_in[3];
    const int* mask = (const int*)d_in[4];
    float* out = (float*)d_out;

    char* ws = (char*)d_ws;
    short* wtq = (short*)ws;                                  // 128KB
    short* wtk = (short*)(ws + 131072);                       // 128KB
    short* Qb  = (short*)(ws + 262144);                       // 32MB
    short* Kb  = (short*)(ws + 262144 + 33554432);            // 32MB

    wtrans_kernel<<<dim3(8, 8, 2), dim3(32, 8), 0, stream>>>(wq, wk, wtq, wtk);
    proj_kernel<<<dim3(1024, 2), 512, 0, stream>>>(q, k, wtq, wtk, Qb, Kb);
    attn_kernel<<<dim3(32, 64), 512, 0, stream>>>(Qb, Kb, mask, out);
}